// Round 6
// baseline (17.994 us; speedup 1.0000x reference)
//
#include <hip/hip_runtime.h>

// Fused quanvolution + FC + log_softmax via MFMA (gfx950).
// Two-phase: (A) lane-coalesced x streaming + trig -> q (bf16) in LDS;
// (B) MFMA logits from LDS A-frags + register B-frags; softmax epilogue.
//
// Phase A unit = one float4 of x (row y, cols 4cx..4cx+3) = 2 within-row
// (even,odd) pixel pairs -> 4 q-values (circuit couples only within-row):
//   za = cos(pa)cos(xa) + sin(pa)sin(xa)sin(xb)
//   zb = cos(pb)cos(xa)cos(xb) + sin(pb)sin(xb)
// even rows -> params (p0,p1), wires 0,1; odd rows -> (p2,p3), wires 2,3.
// q slot: ((y>>1)*14 + col/2)*4 + (y&1)*2 + (col&1)   [q-order K]
//
// Phase B: logits[16][10] = q[16][784] @ w[784][10], mfma_f32_16x16x32_bf16.
// Lane l: i16=l&15 (image/class), g=l>>4. A frag = q_lds[i16][kb*32+8g..+7]
// (ds_read_b128, 16B aligned). B frag = fc_w[class][k..k+7] (L2-hot).
// K split over 4 waves (kb = wv+4I, 25 kblocks; kb>24 skipped), partials
// combined via LDS. C frag (m89): col=lane&15, row=(lane>>4)*4+reg.

typedef __attribute__((ext_vector_type(8))) short short8;
typedef __attribute__((ext_vector_type(4))) float f32x4;

constexpr int WAVES = 4;
constexpr int BLOCK = WAVES * 64;
constexpr int IMGS  = 16;
constexpr int NITER = 7;
constexpr int S2    = 800;            // q_lds row length (bf16 elems), 16B-mult

static __device__ __forceinline__ unsigned pkbf2(float lo, float hi) {
    unsigned r;
    asm("v_cvt_pk_bf16_f32 %0, %1, %2" : "=v"(r) : "v"(lo), "v"(hi));
    return r;                          // [15:0]=bf16(lo), [31:16]=bf16(hi)
}

__global__ __launch_bounds__(BLOCK, 4)
void quanv_mfma(const float* __restrict__ x,
                const float* __restrict__ vqc,
                const float* __restrict__ fc_w,
                const float* __restrict__ fc_b,
                const float* __restrict__ bias,
                float* __restrict__ out,
                int B)
{
    __shared__ __align__(16) unsigned short q_lds[IMGS * S2];  // 25.6 KB
    __shared__ float cpart[3][64 * 4];                          // 3 KB

    const int tid  = threadIdx.x;
    const int lane = tid & 63;
    const int wv   = tid >> 6;
    const int i16  = lane & 15;
    const int g    = lane >> 4;
    const int imgBase = blockIdx.x * IMGS;

    // circuit params
    float S0, C0, S1, C1, S2p, C2p, S3, C3;
    __sincosf(vqc[0], &S0, &C0);
    __sincosf(vqc[1], &S1, &C1);
    __sincosf(vqc[2], &S2p, &C2p);
    __sincosf(vqc[3], &S3, &C3);

    // ---------------- phase A: coalesced x -> q (bf16) in LDS ----------------
    const float4* __restrict__ xf4 =
        reinterpret_cast<const float4*>(x) + (long)imgBase * 196;
    #pragma unroll
    for (int it = 0; it < 13; ++it) {
        const unsigned u = it * BLOCK + tid;      // global float4 idx in slab
        if (it < 12 || u < 3136u) {
            const float4 v = xf4[u];
            const unsigned img = u / 196u;
            const unsigned jv  = u - 196u * img;  // float4 idx within image
            const unsigned y   = jv / 7u;         // image row
            const unsigned cx  = jv - 7u * y;     // float4-col (0..6)
            const unsigned par = y & 1u;

            const float CA = par ? C2p : C0, SA = par ? S2p : S0;
            const float CB = par ? C3  : C1, SB = par ? S3  : S1;

            float sa, ca, sb, cb;
            __sincosf(v.x, &sa, &ca);  __sincosf(v.y, &sb, &cb);
            const float za1 = CA * ca + SA * (sa * sb);
            const float zb1 = CB * (ca * cb) + SB * sb;
            __sincosf(v.z, &sa, &ca);  __sincosf(v.w, &sb, &cb);
            const float za2 = CA * ca + SA * (sa * sb);
            const float zb2 = CB * (ca * cb) + SB * sb;

            // q slot base: patch (y>>1, 2cx), wire offset 2*par  (even)
            const unsigned qb = ((y >> 1) * 14u + 2u * cx) * 4u + 2u * par;
            const unsigned e  = img * S2 + qb;
            *reinterpret_cast<unsigned*>(&q_lds[e])     = pkbf2(za1, zb1);
            *reinterpret_cast<unsigned*>(&q_lds[e + 4]) = pkbf2(za2, zb2);
        }
    }
    // zero the pad region k = 784..799 of every image row
    if (tid < 128) {
        const int img = tid >> 3, o = (tid & 7) << 1;
        *reinterpret_cast<unsigned*>(&q_lds[img * S2 + 784 + o]) = 0u;
    }

    // ---------------- B fragments (fc_w, L2-hot), bf16 regs ----------------
    const int ncl = (i16 < 10) ? i16 : 9;
    const float* __restrict__ wrow = fc_w + ncl * 784;
    short8 bf[NITER];
    #pragma unroll
    for (int I = 0; I < NITER; ++I) {
        int kb = wv + 4 * I; if (kb > 24) kb = 24;     // unused iters: any value
        int k  = kb * 32 + 8 * g; if (k > 776) k = 776; // in-bounds; A=0 covers
        const float4 lo4 = *reinterpret_cast<const float4*>(wrow + k);
        const float4 hi4 = *reinterpret_cast<const float4*>(wrow + k + 4);
        union { unsigned u[4]; short8 s; } t;
        t.u[0] = pkbf2(lo4.x, lo4.y);
        t.u[1] = pkbf2(lo4.z, lo4.w);
        t.u[2] = pkbf2(hi4.x, hi4.y);
        t.u[3] = pkbf2(hi4.z, hi4.w);
        bf[I] = t.s;
    }

    __syncthreads();

    // ---------------- phase B: MFMA over K ----------------
    f32x4 acc = {0.f, 0.f, 0.f, 0.f};
    #pragma unroll
    for (int I = 0; I < NITER; ++I) {
        const int kb = wv + 4 * I;
        if (kb < 25) {                                  // wave-uniform
            const short8 a = *reinterpret_cast<const short8*>(
                &q_lds[i16 * S2 + kb * 32 + 8 * g]);
            acc = __builtin_amdgcn_mfma_f32_16x16x32_bf16(a, bf[I], acc, 0, 0, 0);
        }
    }

    // ---------------- K-split combine + log_softmax ----------------
    if (wv > 0)
        *reinterpret_cast<f32x4*>(&cpart[wv - 1][lane * 4]) = acc;
    __syncthreads();

    if (wv == 0) {
        #pragma unroll
        for (int p = 0; p < 3; ++p)
            acc += *reinterpret_cast<const f32x4*>(&cpart[p][lane * 4]);
        const float bk = (i16 < 10) ? (fc_b[i16] - bias[i16]) : 0.f;

        #pragma unroll
        for (int r = 0; r < 4; ++r) {
            const float lg = acc[r] + bk;
            float mx = (i16 < 10) ? lg : -3.0e38f;
            #pragma unroll
            for (int off = 1; off < 16; off <<= 1)
                mx = fmaxf(mx, __shfl_xor(mx, off, 64));
            float s = (i16 < 10) ? __expf(lg - mx) : 0.f;
            #pragma unroll
            for (int off = 1; off < 16; off <<= 1)
                s += __shfl_xor(s, off, 64);
            const int im = imgBase + g * 4 + r;        // C row = g*4 + reg [m89]
            if (i16 < 10 && im < B)
                out[(long)im * 10 + i16] = lg - mx - __logf(s);
        }
    }
}

extern "C" void kernel_launch(void* const* d_in, const int* in_sizes, int n_in,
                              void* d_out, int out_size, void* d_ws, size_t ws_size,
                              hipStream_t stream) {
    const float* x    = (const float*)d_in[0];
    const float* vqc  = (const float*)d_in[1];
    const float* fc_w = (const float*)d_in[2];
    const float* fc_b = (const float*)d_in[3];
    const float* bias = (const float*)d_in[4];
    float* outp = (float*)d_out;

    const int B = in_sizes[0] / 784;
    const int nblocks = (B + IMGS - 1) / IMGS;
    hipLaunchKernelGGL(quanv_mfma, dim3(nblocks), dim3(BLOCK), 0, stream,
                       x, vqc, fc_w, fc_b, bias, outp, B);
}

// Round 7
// 17.611 us; speedup vs baseline: 1.0217x; 1.0217x over previous
//
#include <hip/hip_runtime.h>

// Fused quanvolution + FC + log_softmax via MFMA (gfx950).
// Two-phase: (A) lane-coalesced x streaming (3-deep load batches) + trig ->
// q (bf16) in LDS; (B) MFMA logits (8-way K-split) + softmax epilogue.
// 512-thread blocks double resident waves vs R6 (grid fixed at B/16 blocks).
//
//   za = cos(pa)cos(xa) + sin(pa)sin(xa)sin(xb)
//   zb = cos(pb)cos(xa)cos(xb) + sin(pb)sin(xb)
// even image rows -> params (p0,p1); odd rows -> (p2,p3).
// q slot: ((y>>1)*14 + col/2)*4 + (y&1)*2 + (col&1)   [q-order K]
//
// Phase B: logits[16][10] = q[16][784] @ w[784][10], mfma_f32_16x16x32_bf16.
// Lane l: i16=l&15 (image/class), g=l>>4. A frag = q_lds[i16][kb*32+8g..+7]
// (ds_read_b128, stride 808 -> bank-balanced). B frag = fc_w[class][k..k+7].
// kb = wv + 8I (25 kblocks over 8 waves), partials combined via q_lds alias.
// C frag (m89): col = lane&15, row = (lane>>4)*4 + reg.

typedef __attribute__((ext_vector_type(8))) short short8;
typedef __attribute__((ext_vector_type(4))) float f32x4;

constexpr int BLOCK = 512;            // 8 waves
constexpr int IMGS  = 16;
constexpr int S2    = 808;            // q_lds stride (bf16): 16B-mult, balanced
constexpr int NIT   = 4;              // ceil(25 kblocks / 8 waves)

static __device__ __forceinline__ unsigned pkbf2(float lo, float hi) {
    unsigned r;
    asm("v_cvt_pk_bf16_f32 %0, %1, %2" : "=v"(r) : "v"(lo), "v"(hi));
    return r;                          // [15:0]=bf16(lo), [31:16]=bf16(hi)
}

__global__ __launch_bounds__(BLOCK, 6)
void quanv_mfma(const float* __restrict__ x,
                const float* __restrict__ vqc,
                const float* __restrict__ fc_w,
                const float* __restrict__ fc_b,
                const float* __restrict__ bias,
                float* __restrict__ out,
                int B)
{
    __shared__ __align__(16) unsigned short q_lds[IMGS * S2];   // 25856 B

    const int tid  = threadIdx.x;
    const int lane = tid & 63;
    const int wv   = tid >> 6;          // 0..7
    const int i16  = lane & 15;         // image (A row) / class (B col)
    const int g    = lane >> 4;         // k-subgroup
    const int imgBase = blockIdx.x * IMGS;

    // circuit params
    float S0, C0, S1, C1, S2p, C2p, S3, C3;
    __sincosf(vqc[0], &S0, &C0);
    __sincosf(vqc[1], &S1, &C1);
    __sincosf(vqc[2], &S2p, &C2p);
    __sincosf(vqc[3], &S3, &C3);

    // zero pad region k = 784..807 (24 bf16 = 12 u32 per image)
    if (tid < 192) {
        const unsigned im = (unsigned)tid / 12u;
        const unsigned o  = (unsigned)tid - 12u * im;
        *reinterpret_cast<unsigned*>(&q_lds[im * S2 + 784 + 2 * o]) = 0u;
    }

    // ---------------- phase A: coalesced x -> q (bf16) in LDS ----------------
    const float4* __restrict__ xf4 =
        reinterpret_cast<const float4*>(x) + (long)imgBase * 196;

    // unit u = it*512 + tid; img = u/196, jv = u%196 tracked incrementally
    unsigned img = (unsigned)tid / 196u;
    unsigned jv  = (unsigned)tid - 196u * img;

    auto process = [&](float4 v, unsigned im, unsigned j) {
        const unsigned y   = (j * 1171u) >> 13;        // j/7 (exact, j<196)
        const unsigned cx  = j - 7u * y;               // float4-col 0..6
        const unsigned par = y & 1u;
        const float CA = par ? C2p : C0, SA = par ? S2p : S0;
        const float CB = par ? C3  : C1, SB = par ? S3  : S1;
        float sa, ca, sb, cb;
        __sincosf(v.x, &sa, &ca);  __sincosf(v.y, &sb, &cb);
        const float za1 = CA * ca + SA * (sa * sb);
        const float zb1 = CB * (ca * cb) + SB * sb;
        __sincosf(v.z, &sa, &ca);  __sincosf(v.w, &sb, &cb);
        const float za2 = CA * ca + SA * (sa * sb);
        const float zb2 = CB * (ca * cb) + SB * sb;
        const unsigned e = im * S2 + (y >> 1) * 56u + 8u * cx + 2u * par;
        *reinterpret_cast<unsigned*>(&q_lds[e])     = pkbf2(za1, zb1);
        *reinterpret_cast<unsigned*>(&q_lds[e + 4]) = pkbf2(za2, zb2);
    };

    #pragma unroll
    for (int bt = 0; bt < 2; ++bt) {
        // 3-deep load batch: issue all global loads before any dependent use
        const float4 r0 = xf4[(bt * 3 + 0) * BLOCK + tid];
        const float4 r1 = xf4[(bt * 3 + 1) * BLOCK + tid];
        const float4 r2 = xf4[(bt * 3 + 2) * BLOCK + tid];
        process(r0, img, jv);
        img += 2; jv += 120; if (jv >= 196) { jv -= 196; img += 1; }
        process(r1, img, jv);
        img += 2; jv += 120; if (jv >= 196) { jv -= 196; img += 1; }
        process(r2, img, jv);
        img += 2; jv += 120; if (jv >= 196) { jv -= 196; img += 1; }
    }
    if (tid < 64) {                      // tail: u = 3072+tid (wave 0 only)
        const float4 r = xf4[6 * BLOCK + tid];
        process(r, img, jv);
    }

    __syncthreads();

    // ---------------- phase B: B-frags + MFMA over K ----------------
    const int ncl = (i16 < 10) ? i16 : 9;
    const float* __restrict__ wrow = fc_w + ncl * 784;
    short8 bf[NIT];
    #pragma unroll
    for (int I = 0; I < NIT; ++I) {
        const int kb = wv + 8 * I;
        if (kb < 25) {
            int k = kb * 32 + 8 * g;
            if (k > 776) k = 776;               // in-bounds; pad-zero A covers
            const float4 lo4 = *reinterpret_cast<const float4*>(wrow + k);
            const float4 hi4 = *reinterpret_cast<const float4*>(wrow + k + 4);
            union { unsigned u[4]; short8 s; } t;
            t.u[0] = pkbf2(lo4.x, lo4.y);
            t.u[1] = pkbf2(lo4.z, lo4.w);
            t.u[2] = pkbf2(hi4.x, hi4.y);
            t.u[3] = pkbf2(hi4.z, hi4.w);
            bf[I] = t.s;
        }
    }

    f32x4 acc = {0.f, 0.f, 0.f, 0.f};
    #pragma unroll
    for (int I = 0; I < NIT; ++I) {
        const int kb = wv + 8 * I;
        if (kb < 25) {                          // wave-uniform
            const short8 a = *reinterpret_cast<const short8*>(
                &q_lds[i16 * S2 + kb * 32 + 8 * g]);
            acc = __builtin_amdgcn_mfma_f32_16x16x32_bf16(a, bf[I], acc, 0, 0, 0);
        }
    }

    // ---------------- K-split combine (cpart aliases q_lds) ----------------
    __syncthreads();                            // all q_lds reads complete
    float* const cpart = reinterpret_cast<float*>(q_lds);   // 7*256*4 B used
    if (wv > 0)
        *reinterpret_cast<f32x4*>(&cpart[(wv - 1) * 256 + lane * 4]) = acc;
    __syncthreads();

    if (wv == 0) {
        #pragma unroll
        for (int p = 0; p < 7; ++p)
            acc += *reinterpret_cast<const f32x4*>(&cpart[p * 256 + lane * 4]);
        const float bk = (i16 < 10) ? (fc_b[i16] - bias[i16]) : 0.f;

        #pragma unroll
        for (int r = 0; r < 4; ++r) {
            const float lg = acc[r] + bk;
            float mx = (i16 < 10) ? lg : -3.0e38f;
            #pragma unroll
            for (int off = 1; off < 16; off <<= 1)
                mx = fmaxf(mx, __shfl_xor(mx, off, 64));
            float s = (i16 < 10) ? __expf(lg - mx) : 0.f;
            #pragma unroll
            for (int off = 1; off < 16; off <<= 1)
                s += __shfl_xor(s, off, 64);
            const int im = imgBase + g * 4 + r;   // C row = g*4 + reg [m89]
            if (i16 < 10 && im < B)
                out[(long)im * 10 + i16] = lg - mx - __logf(s);
        }
    }
}

extern "C" void kernel_launch(void* const* d_in, const int* in_sizes, int n_in,
                              void* d_out, int out_size, void* d_ws, size_t ws_size,
                              hipStream_t stream) {
    const float* x    = (const float*)d_in[0];
    const float* vqc  = (const float*)d_in[1];
    const float* fc_w = (const float*)d_in[2];
    const float* fc_b = (const float*)d_in[3];
    const float* bias = (const float*)d_in[4];
    float* outp = (float*)d_out;

    const int B = in_sizes[0] / 784;
    const int nblocks = (B + IMGS - 1) / IMGS;
    hipLaunchKernelGGL(quanv_mfma, dim3(nblocks), dim3(BLOCK), 0, stream,
                       x, vqc, fc_w, fc_b, bias, outp, B);
}